// Round 1
// 1949.048 us; speedup vs baseline: 2.7611x; 2.7611x over previous
//
#include <hip/hip_runtime.h>

typedef unsigned short u16;
typedef unsigned int u32;
typedef __attribute__((ext_vector_type(8))) short short8;
typedef __attribute__((ext_vector_type(4))) float floatx4;

#define B_ 16
#define S_ 64
#define H_ 512
#define V_ 32000
#define G3 1536   // 3*H
#define TD 63     // T-1
#define MROWS 1008
#define NBLK 16   // rec_kernel blocks (one per batch AND one per 32-col slice)

__device__ __forceinline__ float b2f(u16 u) {
  union { u32 i; float f; } c; c.i = ((u32)u) << 16; return c.f;
}
__device__ __forceinline__ u16 f2b(float f) {
  union { float f; u32 i; } c; c.f = f;
  u32 u = c.i;
  return (u16)((u + 0x7FFFu + ((u >> 16) & 1u)) >> 16);  // RNE
}
__device__ __forceinline__ short8 pack8(float4 a, float4 b) {
  short8 r;
  r[0] = (short)f2b(a.x); r[1] = (short)f2b(a.y); r[2] = (short)f2b(a.z); r[3] = (short)f2b(a.w);
  r[4] = (short)f2b(b.x); r[5] = (short)f2b(b.y); r[6] = (short)f2b(b.z); r[7] = (short)f2b(b.w);
  return r;
}

// ---------------- embedding gather (f32 -> bf16) ----------------
__global__ void __launch_bounds__(256) gather_kernel(
    const int* __restrict__ x, const int* __restrict__ y,
    const float* __restrict__ emb_enc, const float* __restrict__ emb_dec,
    u16* __restrict__ ex, u16* __restrict__ ey)
{
  const int r = blockIdx.x, tid = threadIdx.x;
  if (r < B_ * S_) {                       // encoder row m = b*64+s
    int tok = x[r];
    float2 v = ((const float2*)(emb_enc + (size_t)tok * H_))[tid];
    ((u32*)(ex + (size_t)r * H_))[tid] = (u32)f2b(v.x) | ((u32)f2b(v.y) << 16);
  } else {                                 // decoder row m = t*16+b
    int m = r - B_ * S_;
    int t = m >> 4, b = m & 15;
    int tok = y[b * 64 + t];
    float2 v = ((const float2*)(emb_dec + (size_t)tok * H_))[tid];
    ((u32*)(ey + (size_t)m * H_))[tid] = (u32)f2b(v.x) | ((u32)f2b(v.y) << 16);
  }
}

// ---------------- bf16-MFMA GEMM: C = A @ B^T + bias ----------------
// A:[M,512] bf16, B:[N,512] f32 (converted to bf16 while staging), bias f32[N]
// MODE 0: C fp32 [M,N].  MODE 1: C fp32 into d_out, row remap m=t*16+b -> (b*63+t)
template <int MODE>
__global__ void __launch_bounds__(256) gemm_bt(
    const u16* __restrict__ A, const float* __restrict__ Bm,
    const float* __restrict__ bias, void* __restrict__ Cout, int M, int N)
{
  __shared__ u16 As[64 * 40];
  __shared__ u16 Bs[128 * 40];
  const int tid = threadIdx.x;
  const int wave = tid >> 6, lane = tid & 63;
  const int l15 = lane & 15, quad = lane >> 4;
  const int m0 = blockIdx.y * 64, n0 = blockIdx.x * 128;
  floatx4 acc[4][2] = {};

  for (int kk = 0; kk < 512; kk += 32) {
    {
      int row = tid >> 2, ch = tid & 3;
      short8 v = {};
      int gm = m0 + row;
      if (gm < M) v = *(const short8*)(A + (size_t)gm * 512 + kk + ch * 8);
      *(short8*)(As + row * 40 + ch * 8) = v;
    }
#pragma unroll
    for (int i = 0; i < 4; ++i) {
      int idx = tid + i * 256;
      int row = idx >> 3, c4 = idx & 7;
      int gn = n0 + row;
      float4 w = *(const float4*)(Bm + (size_t)gn * 512 + kk + c4 * 4);
      uint2 p;
      p.x = (u32)f2b(w.x) | ((u32)f2b(w.y) << 16);
      p.y = (u32)f2b(w.z) | ((u32)f2b(w.w) << 16);
      *(uint2*)(Bs + row * 40 + c4 * 4) = p;
    }
    __syncthreads();
    short8 af[4], bfr[2];
#pragma unroll
    for (int mt = 0; mt < 4; ++mt)
      af[mt] = *(const short8*)(As + (mt * 16 + l15) * 40 + quad * 8);
#pragma unroll
    for (int nt = 0; nt < 2; ++nt)
      bfr[nt] = *(const short8*)(Bs + (wave * 32 + nt * 16 + l15) * 40 + quad * 8);
#pragma unroll
    for (int mt = 0; mt < 4; ++mt)
#pragma unroll
      for (int nt = 0; nt < 2; ++nt)
        acc[mt][nt] = __builtin_amdgcn_mfma_f32_16x16x32_bf16(af[mt], bfr[nt], acc[mt][nt], 0, 0, 0);
    __syncthreads();
  }
#pragma unroll
  for (int mt = 0; mt < 4; ++mt) {
#pragma unroll
    for (int nt = 0; nt < 2; ++nt) {
      int gn = n0 + wave * 32 + nt * 16 + l15;
      float bv = bias[gn];
#pragma unroll
      for (int r = 0; r < 4; ++r) {
        int gm = m0 + mt * 16 + quad * 4 + r;  // C/D: col=lane&15, row=quad*4+reg
        if (gm < M) {
          float v = acc[mt][nt][r] + bv;
          if (MODE == 0) {
            ((float*)Cout)[(size_t)gm * N + gn] = v;
          } else {
            int tt = gm >> 4, bb = gm & 15;
            ((float*)Cout)[((size_t)bb * TD + tt) * V_ + gn] = v;
          }
        }
      }
    }
  }
}

// ---------------- cooperative recurrence ----------------
// 16 blocks x 512 threads. Block k owns h-columns [32k, 32k+32).
// Weights live in REGISTERS as bf16 MFMA B-fragments (read from HBM once):
//   waves 0..5: gate tiles (sub=w%3 in {r,z,n}, half=w/3) for enc+dec (wf[0..15]=enc, wf[16..31]=dec)
//   waves 6..7: W_c output tiles (wf[0..31], K=1024)
// Cross-block h exchange: bf16 ha[2][16][1024] (cols 0..511 = h, 512..1023 = attn),
// double-buffered by step parity; custom device-scope barrier between phases.
struct RecArgs {
  const float* gi_enc;   // [1024][1536]  row = b*64+s
  const float* gi_dec;   // [1008][1536]  row = t*16+b
  const float* Whe;      // [1536][512] raw W_hh_e
  const float* Whd;      // [1536][512] raw W_hh_d
  const float* Wc;       // [512][1024] raw W_c
  const float* bhe;      // [1536]
  const float* bhd;      // [1536]
  const float* bc;       // [512]
  u16* eo;               // enc_out bf16 [16][64][512]
  u16* ha;               // [2][16][1024] bf16 (h | attn)
  u16* D;                // [1008][512] bf16, row = t*16+b
  int* bar;              // bar[0]=count, bar[32]=generation
};

__device__ __forceinline__ void gridbar(int* bar, int target) {
  __syncthreads();
  if (threadIdx.x == 0) {
    __builtin_amdgcn_fence(__ATOMIC_RELEASE, "agent");
    int prev = __hip_atomic_fetch_add(bar, 1, __ATOMIC_ACQ_REL, __HIP_MEMORY_SCOPE_AGENT);
    if (prev == NBLK - 1) {
      __hip_atomic_store(bar, 0, __ATOMIC_RELAXED, __HIP_MEMORY_SCOPE_AGENT);
      __hip_atomic_store(bar + 32, target, __ATOMIC_RELEASE, __HIP_MEMORY_SCOPE_AGENT);
    } else {
      while (__hip_atomic_load(bar + 32, __ATOMIC_RELAXED, __HIP_MEMORY_SCOPE_AGENT) < target) {}
    }
    __builtin_amdgcn_fence(__ATOMIC_ACQUIRE, "agent");
  }
  __syncthreads();
}

// One GRU gate+update phase. p = read parity (reads ha[p], writes ha[p^1]).
template <int ISENC>
__device__ __forceinline__ void gate_phase(const RecArgs& a, int wave, int l15, int quad,
    int J, int step, int p, const short8* wf, float bh, float* hreg,
    float (&lds_rz)[2][2][16][16])
{
  if (wave < 6) {
    const int sub = wave % 3, half = wave / 3;
    const int jc = J + half * 16 + l15;
    const float* gi = ISENC ? a.gi_enc : a.gi_dec;
    float giv[4];
#pragma unroll
    for (int r = 0; r < 4; ++r) {
      const int b = quad * 4 + r;
      const int row = ISENC ? (b * 64 + step) : (step * 16 + b);
      giv[r] = gi[(size_t)row * G3 + sub * 512 + jc];
    }
    const u16* hb = a.ha + p * 16384 + l15 * 1024 + quad * 8;
    short8 af[16];
#pragma unroll
    for (int kk = 0; kk < 16; ++kk) af[kk] = *(const short8*)(hb + kk * 32);
    floatx4 acc = {0.f, 0.f, 0.f, 0.f};
#pragma unroll
    for (int kk = 0; kk < 16; ++kk)
      acc = __builtin_amdgcn_mfma_f32_16x16x32_bf16(af[kk], wf[(ISENC ? 0 : 16) + kk], acc, 0, 0, 0);
    if (sub < 2) {
#pragma unroll
      for (int r = 0; r < 4; ++r)
        lds_rz[sub][half][quad * 4 + r][l15] = acc[r] + bh + giv[r];
      __syncthreads();
    } else {
      __syncthreads();
      const int pn = p ^ 1;
#pragma unroll
      for (int r = 0; r < 4; ++r) {
        const int b = quad * 4 + r;
        const float rp = lds_rz[0][half][b][l15];
        const float zp = lds_rz[1][half][b][l15];
        const float rr = 1.f / (1.f + __expf(-rp));
        const float zz = 1.f / (1.f + __expf(-zp));
        const float nn = tanhf(giv[r] + rr * (acc[r] + bh));   // n = tanh(gi_n + r*(gh_n + bhh_n))
        const float hv = (1.f - zz) * nn + zz * hreg[r];
        hreg[r] = hv;
        const u16 h16 = f2b(hv);
        a.ha[pn * 16384 + b * 1024 + jc] = h16;
        if (ISENC) a.eo[((size_t)(b * 64 + step)) * 512 + jc] = h16;
      }
    }
  } else {
    __syncthreads();
  }
}

// Attention for batch bb (whole block, 512 threads). Reads h=ha[pn][bb][0:512] and
// enc_out; writes attn into ha[pn][bb][512:1024].
__device__ __forceinline__ void attn_phase(const RecArgs& a, int bb, int pn, int tid,
    float (&sc)[64][9], float (&wts)[64])
{
  const u16* eo = a.eo + (size_t)bb * 64 * 512;
  {
    const int s = tid >> 3, q = tid & 7;
    const u16* ep = eo + s * 512 + q * 64;
    const u16* hp = a.ha + pn * 16384 + bb * 1024 + q * 64;
    float acc = 0.f;
#pragma unroll
    for (int u = 0; u < 8; ++u) {
      short8 e8 = *(const short8*)(ep + u * 8);
      short8 h8 = *(const short8*)(hp + u * 8);
#pragma unroll
      for (int i = 0; i < 8; ++i) acc += b2f((u16)e8[i]) * b2f((u16)h8[i]);
    }
    sc[s][q] = acc;
  }
  __syncthreads();
  if (tid < 64) {
    float v = 0.f;
#pragma unroll
    for (int u = 0; u < 8; ++u) v += sc[tid][u];
    float m = v;
#pragma unroll
    for (int d = 1; d < 64; d <<= 1) m = fmaxf(m, __shfl_xor(m, d));
    float e = __expf(v - m);
    float sum = e;
#pragma unroll
    for (int d = 1; d < 64; d <<= 1) sum += __shfl_xor(sum, d);
    wts[tid] = e / sum;
  }
  __syncthreads();
  {
    const int j = tid;
    const u16* ep = eo + j;
    float acc = 0.f;
#pragma unroll 8
    for (int s2 = 0; s2 < 64; ++s2) acc += wts[s2] * b2f(ep[s2 * 512]);
    a.ha[pn * 16384 + bb * 1024 + 512 + j] = f2b(acc);
  }
}

__global__ void __launch_bounds__(512) rec_kernel(RecArgs a) {
  __shared__ float lds_rz[2][2][16][16];
  __shared__ float sc[64][9];
  __shared__ float wts[64];
  const int tid = threadIdx.x;
  const int wave = tid >> 6, lane = tid & 63;
  const int l15 = lane & 15, quad = lane >> 4;
  const int J = blockIdx.x * 32;
  const int sub = wave % 3, half = wave / 3;

  // ---- one-time: stage weight fragments into registers (bf16) ----
  short8 wf[32];
  float bhe = 0.f, bhd = 0.f, bcv = 0.f;
  if (wave < 6) {
    const int row = sub * 512 + J + half * 16 + l15;   // gate row of W_hh
    const float* pe = a.Whe + (size_t)row * 512 + quad * 8;
    const float* pd = a.Whd + (size_t)row * 512 + quad * 8;
#pragma unroll
    for (int kk = 0; kk < 16; ++kk) {
      wf[kk]      = pack8(*(const float4*)(pe + kk * 32), *(const float4*)(pe + kk * 32 + 4));
      wf[16 + kk] = pack8(*(const float4*)(pd + kk * 32), *(const float4*)(pd + kk * 32 + 4));
    }
    const int jc = J + half * 16 + l15;
    bhe = a.bhe[sub * 512 + jc];
    bhd = a.bhd[sub * 512 + jc];
  } else {
    const int row = J + (wave - 6) * 16 + l15;         // W_c output row
    const float* pc = a.Wc + (size_t)row * 1024 + quad * 8;
#pragma unroll
    for (int kk = 0; kk < 32; ++kk)
      wf[kk] = pack8(*(const float4*)(pc + kk * 32), *(const float4*)(pc + kk * 32 + 4));
    bcv = a.bc[row];
  }

  float hreg[4] = {0.f, 0.f, 0.f, 0.f};
  // zero-init h buffer 0 (own columns cover all 512 across the 16 blocks)
  if (wave < 6 && sub == 2) {
#pragma unroll
    for (int r = 0; r < 4; ++r)
      a.ha[(quad * 4 + r) * 1024 + (J + half * 16 + l15)] = 0;
  }
  int bt = 0;
  gridbar(a.bar, ++bt);

  // ---- encoder: 1 barrier / step ----
  for (int s = 0; s < S_; ++s) {
    gate_phase<1>(a, wave, l15, quad, J, s, s & 1, wf, bhe, hreg, lds_rz);
    gridbar(a.bar, ++bt);
  }

  // ---- decoder: 2 barriers / step ----
  for (int t = 0; t < TD; ++t) {
    const int p = t & 1, pn = p ^ 1;      // (64+t)&1 == t&1
    gate_phase<0>(a, wave, l15, quad, J, t, p, wf, bhd, hreg, lds_rz);
    gridbar(a.bar, ++bt);
    attn_phase(a, (int)blockIdx.x, pn, tid, sc, wts);
    gridbar(a.bar, ++bt);
    if (wave >= 6) {                      // d = tanh([h;attn] @ Wc^T + bc), bf16 out
      const u16* hb = a.ha + pn * 16384 + l15 * 1024 + quad * 8;
      floatx4 acc = {0.f, 0.f, 0.f, 0.f};
#pragma unroll
      for (int h4 = 0; h4 < 4; ++h4) {
        short8 af[8];
#pragma unroll
        for (int u2 = 0; u2 < 8; ++u2) af[u2] = *(const short8*)(hb + (h4 * 8 + u2) * 32);
#pragma unroll
        for (int u2 = 0; u2 < 8; ++u2)
          acc = __builtin_amdgcn_mfma_f32_16x16x32_bf16(af[u2], wf[h4 * 8 + u2], acc, 0, 0, 0);
      }
      const int col = J + (wave - 6) * 16 + l15;
#pragma unroll
      for (int r = 0; r < 4; ++r)
        a.D[((size_t)(t * 16 + quad * 4 + r)) * 512 + col] = f2b(tanhf(acc[r] + bcv));
    }
  }
}

// ---------------- loss (f32 logits) ----------------
__global__ void __launch_bounds__(256) loss_rows_kernel(
    const float* __restrict__ logits, const int* __restrict__ y, float* __restrict__ nll)
{
  __shared__ float wred[4];
  const int m = blockIdx.x;               // m = t*16+b
  const int t = m >> 4, b = m & 15;
  const float* row = logits + ((size_t)b * TD + t) * V_;
  const int tid = threadIdx.x;
  const int lane = tid & 63, wave = tid >> 6;

  float mx = -1e30f;
  for (int c = tid; c < 8000; c += 256) {
    float4 v = ((const float4*)row)[c];
    mx = fmaxf(mx, fmaxf(fmaxf(v.x, v.y), fmaxf(v.z, v.w)));
  }
#pragma unroll
  for (int d = 1; d < 64; d <<= 1) mx = fmaxf(mx, __shfl_xor(mx, d));
  if (lane == 0) wred[wave] = mx;
  __syncthreads();
  mx = fmaxf(fmaxf(wred[0], wred[1]), fmaxf(wred[2], wred[3]));
  __syncthreads();

  float sum = 0.f;
  for (int c = tid; c < 8000; c += 256) {
    float4 v = ((const float4*)row)[c];
    sum += __expf(v.x - mx) + __expf(v.y - mx) + __expf(v.z - mx) + __expf(v.w - mx);
  }
#pragma unroll
  for (int d = 1; d < 64; d <<= 1) sum += __shfl_xor(sum, d);
  if (lane == 0) wred[wave] = sum;
  __syncthreads();
  if (tid == 0) {
    float stot = wred[0] + wred[1] + wred[2] + wred[3];
    int tok = y[b * 64 + t + 1];
    nll[m] = mx + logf(stot) - row[tok];
  }
}

__global__ void __launch_bounds__(256) loss_final_kernel(const float* __restrict__ nll, float* __restrict__ out) {
  __shared__ float wred[4];
  const int tid = threadIdx.x;
  float s = 0.f;
  for (int i = tid; i < MROWS; i += 256) s += nll[i];
#pragma unroll
  for (int d = 1; d < 64; d <<= 1) s += __shfl_xor(s, d);
  if ((tid & 63) == 0) wred[tid >> 6] = s;
  __syncthreads();
  if (tid == 0) out[0] = (wred[0] + wred[1] + wred[2] + wred[3]) / 1008.f;
}

// ---------------- launch ----------------
extern "C" void kernel_launch(void* const* d_in, const int* in_sizes, int n_in,
                              void* d_out, int out_size, void* d_ws, size_t ws_size,
                              hipStream_t stream)
{
  const int*   x       = (const int*)d_in[0];
  const int*   y       = (const int*)d_in[1];
  const float* emb_enc = (const float*)d_in[2];
  const float* W_ih_e  = (const float*)d_in[3];
  const float* W_hh_e  = (const float*)d_in[4];
  const float* b_ih_e  = (const float*)d_in[5];
  const float* b_hh_e  = (const float*)d_in[6];
  const float* emb_dec = (const float*)d_in[7];
  const float* W_ih_d  = (const float*)d_in[8];
  const float* W_hh_d  = (const float*)d_in[9];
  const float* b_ih_d  = (const float*)d_in[10];
  const float* b_hh_d  = (const float*)d_in[11];
  const float* W_c     = (const float*)d_in[12];
  const float* b_c     = (const float*)d_in[13];
  const float* W_out   = (const float*)d_in[14];
  const float* b_out   = (const float*)d_in[15];

  // ws layout (16,715,968 B total — under the proven 17.8 MB footprint)
  char* ws = (char*)d_ws;
  float* gi_enc = (float*)(ws + 0);           //  6,291,456
  float* gi_dec = (float*)(ws + 6291456);     //  6,193,152  -> 12,484,608
  u16* embx     = (u16*)(ws + 12484608);      //  1,048,576  -> 13,533,184
  u16* emby     = (u16*)(ws + 13533184);      //  1,032,192  -> 14,565,376
  u16* Dm       = (u16*)(ws + 14565376);      //  1,032,192  -> 15,597,568
  u16* eo16     = (u16*)(ws + 15597568);      //  1,048,576  -> 16,646,144
  u16* ha16     = (u16*)(ws + 16646144);      //     65,536  -> 16,711,680
  float* nll    = (float*)(ws + 16711680);    //      4,032  -> 16,715,712
  int* bar      = (int*)(ws + 16715712);      //        256

  hipMemsetAsync(bar, 0, 256, stream);        // barrier count+generation (graph-capture safe)

  gather_kernel<<<dim3(B_ * S_ + MROWS), dim3(256), 0, stream>>>(x, y, emb_enc, emb_dec, embx, emby);

  gemm_bt<0><<<dim3(12, 16), dim3(256), 0, stream>>>(embx, W_ih_e, b_ih_e, (void*)gi_enc, 1024, G3);
  gemm_bt<0><<<dim3(12, 16), dim3(256), 0, stream>>>(emby, W_ih_d, b_ih_d, (void*)gi_dec, MROWS, G3);

  RecArgs ra{gi_enc, gi_dec, W_hh_e, W_hh_d, W_c, b_hh_e, b_hh_d, b_c, eo16, ha16, Dm, bar};
  rec_kernel<<<dim3(NBLK), dim3(512), 0, stream>>>(ra);

  gemm_bt<1><<<dim3(250, 16), dim3(256), 0, stream>>>(Dm, W_out, b_out, d_out, MROWS, V_);
  loss_rows_kernel<<<dim3(MROWS), dim3(256), 0, stream>>>((const float*)d_out, y, nll);
  loss_final_kernel<<<dim3(1), dim3(256), 0, stream>>>(nll, ((float*)d_out) + (size_t)MROWS * V_);
}

// Round 2
// 1230.932 us; speedup vs baseline: 4.3719x; 1.5834x over previous
//
#include <hip/hip_runtime.h>

typedef unsigned short u16;
typedef unsigned int u32;
typedef __attribute__((ext_vector_type(8))) short short8;
typedef __attribute__((ext_vector_type(4))) float floatx4;

#define B_ 16
#define S_ 64
#define H_ 512
#define V_ 32000
#define G3 1536   // 3*H
#define TD 63     // T-1
#define MROWS 1008
#define NBLK 16   // rec_kernel blocks (one per 32-col slice of h)

__device__ __forceinline__ float b2f(u16 u) {
  union { u32 i; float f; } c; c.i = ((u32)u) << 16; return c.f;
}
__device__ __forceinline__ u16 f2b(float f) {
  union { float f; u32 i; } c; c.f = f;
  u32 u = c.i;
  return (u16)((u + 0x7FFFu + ((u >> 16) & 1u)) >> 16);  // RNE
}
__device__ __forceinline__ short8 pack8(float4 a, float4 b) {
  short8 r;
  r[0] = (short)f2b(a.x); r[1] = (short)f2b(a.y); r[2] = (short)f2b(a.z); r[3] = (short)f2b(a.w);
  r[4] = (short)f2b(b.x); r[5] = (short)f2b(b.y); r[6] = (short)f2b(b.z); r[7] = (short)f2b(b.w);
  return r;
}

// ---------------- embedding gather (f32 -> bf16) ----------------
__global__ void __launch_bounds__(256) gather_kernel(
    const int* __restrict__ x, const int* __restrict__ y,
    const float* __restrict__ emb_enc, const float* __restrict__ emb_dec,
    u16* __restrict__ ex, u16* __restrict__ ey)
{
  const int r = blockIdx.x, tid = threadIdx.x;
  if (r < B_ * S_) {                       // encoder row m = b*64+s
    int tok = x[r];
    float2 v = ((const float2*)(emb_enc + (size_t)tok * H_))[tid];
    ((u32*)(ex + (size_t)r * H_))[tid] = (u32)f2b(v.x) | ((u32)f2b(v.y) << 16);
  } else {                                 // decoder row m = t*16+b
    int m = r - B_ * S_;
    int t = m >> 4, b = m & 15;
    int tok = y[b * 64 + t];
    float2 v = ((const float2*)(emb_dec + (size_t)tok * H_))[tid];
    ((u32*)(ey + (size_t)m * H_))[tid] = (u32)f2b(v.x) | ((u32)f2b(v.y) << 16);
  }
}

// ---------------- bf16-MFMA GEMM: C = A @ B^T + bias ----------------
// A:[M,K] bf16, B:[N,K] f32 (converted to bf16 while staging), bias f32[N]
// MODE 0: C fp32 [M,N].
// MODE 1: C fp32 into d_out, row remap m=t*16+b -> (b*63+t)
// MODE 2: C = tanh(.) -> bf16 [M,N]
template <int MODE>
__global__ void __launch_bounds__(256) gemm_bt(
    const u16* __restrict__ A, const float* __restrict__ Bm,
    const float* __restrict__ bias, void* __restrict__ Cout, int M, int N, int K)
{
  __shared__ u16 As[64 * 40];
  __shared__ u16 Bs[128 * 40];
  const int tid = threadIdx.x;
  const int wave = tid >> 6, lane = tid & 63;
  const int l15 = lane & 15, quad = lane >> 4;
  const int m0 = blockIdx.y * 64, n0 = blockIdx.x * 128;
  floatx4 acc[4][2] = {};

  for (int kk = 0; kk < K; kk += 32) {
    {
      int row = tid >> 2, ch = tid & 3;
      short8 v = {};
      int gm = m0 + row;
      if (gm < M) v = *(const short8*)(A + (size_t)gm * K + kk + ch * 8);
      *(short8*)(As + row * 40 + ch * 8) = v;
    }
#pragma unroll
    for (int i = 0; i < 4; ++i) {
      int idx = tid + i * 256;
      int row = idx >> 3, c4 = idx & 7;
      int gn = n0 + row;
      float4 w = *(const float4*)(Bm + (size_t)gn * K + kk + c4 * 4);
      uint2 p;
      p.x = (u32)f2b(w.x) | ((u32)f2b(w.y) << 16);
      p.y = (u32)f2b(w.z) | ((u32)f2b(w.w) << 16);
      *(uint2*)(Bs + row * 40 + c4 * 4) = p;
    }
    __syncthreads();
    short8 af[4], bfr[2];
#pragma unroll
    for (int mt = 0; mt < 4; ++mt)
      af[mt] = *(const short8*)(As + (mt * 16 + l15) * 40 + quad * 8);
#pragma unroll
    for (int nt = 0; nt < 2; ++nt)
      bfr[nt] = *(const short8*)(Bs + (wave * 32 + nt * 16 + l15) * 40 + quad * 8);
#pragma unroll
    for (int mt = 0; mt < 4; ++mt)
#pragma unroll
      for (int nt = 0; nt < 2; ++nt)
        acc[mt][nt] = __builtin_amdgcn_mfma_f32_16x16x32_bf16(af[mt], bfr[nt], acc[mt][nt], 0, 0, 0);
    __syncthreads();
  }
#pragma unroll
  for (int mt = 0; mt < 4; ++mt) {
#pragma unroll
    for (int nt = 0; nt < 2; ++nt) {
      int gn = n0 + wave * 32 + nt * 16 + l15;
      float bv = bias[gn];
#pragma unroll
      for (int r = 0; r < 4; ++r) {
        int gm = m0 + mt * 16 + quad * 4 + r;  // C/D: col=lane&15, row=quad*4+reg
        if (gm < M) {
          float v = acc[mt][nt][r] + bv;
          if (MODE == 0) {
            ((float*)Cout)[(size_t)gm * N + gn] = v;
          } else if (MODE == 1) {
            int tt = gm >> 4, bb = gm & 15;
            ((float*)Cout)[((size_t)bb * TD + tt) * V_ + gn] = v;
          } else {
            ((u16*)Cout)[(size_t)gm * N + gn] = f2b(tanhf(v));
          }
        }
      }
    }
  }
}

// ---------------- cooperative recurrence (GRU chain ONLY) ----------------
// 16 blocks x 384 threads. Block k owns h-columns [32k, 32k+32).
// Weights (W_hh enc+dec gate slices) live in registers as bf16 MFMA B-frags.
// Cross-block h exchange: bf16 ha[2][16][512], double-buffered by step parity.
// Attention / W_c / logits are all hoisted OUT of the loop (no in-loop deps).
struct RecArgs {
  const float* gi_enc;   // [1024][1536]  row = b*64+s
  const float* gi_dec;   // [1008][1536]  row = t*16+b
  const float* Whe;      // [1536][512] raw W_hh_e
  const float* Whd;      // [1536][512] raw W_hh_d
  const float* bhe;      // [1536]
  const float* bhd;      // [1536]
  u16* eo;               // enc_out bf16 [16][64][512]
  u16* ha;               // [2][16][512] bf16 h exchange
  u16* hcat;             // [1008][1024] bf16: cols 0..511 = h_t (written here), 512..1023 = attn (later)
  int* bar;              // 16 arrival slots, 128B apart, generation-tagged
};

// Symmetric generation barrier: no RMW contention, no reset round.
__device__ __forceinline__ void gridbar(int* slots, int gen) {
  __syncthreads();
  if (threadIdx.x < 16) {
    if (threadIdx.x == 0) {
      __builtin_amdgcn_fence(__ATOMIC_RELEASE, "agent");
      __hip_atomic_store(slots + (int)blockIdx.x * 32, gen, __ATOMIC_RELAXED, __HIP_MEMORY_SCOPE_AGENT);
    }
    while (__hip_atomic_load(slots + (int)threadIdx.x * 32, __ATOMIC_RELAXED, __HIP_MEMORY_SCOPE_AGENT) < gen) {}
    __builtin_amdgcn_fence(__ATOMIC_ACQUIRE, "agent");
  }
  __syncthreads();
}

// One GRU gate+update phase. p = read parity (reads ha[p], writes ha[p^1]).
template <int ISENC>
__device__ __forceinline__ void gate_phase(const RecArgs& a, int wave, int l15, int quad,
    int J, int step, int p, const short8* wf, float bh, float* hreg,
    float (&lds_rz)[2][2][16][16])
{
  const int sub = wave % 3, half = wave / 3;
  const int jc = J + half * 16 + l15;
  const float* gi = ISENC ? a.gi_enc : a.gi_dec;
  float giv[4];
#pragma unroll
  for (int r = 0; r < 4; ++r) {
    const int b = quad * 4 + r;
    const int row = ISENC ? (b * 64 + step) : (step * 16 + b);
    giv[r] = gi[(size_t)row * G3 + sub * 512 + jc];
  }
  const u16* hb = a.ha + p * 8192 + l15 * 512 + quad * 8;
  short8 af[16];
#pragma unroll
  for (int kk = 0; kk < 16; ++kk) af[kk] = *(const short8*)(hb + kk * 32);
  floatx4 acc = {0.f, 0.f, 0.f, 0.f};
#pragma unroll
  for (int kk = 0; kk < 16; ++kk)
    acc = __builtin_amdgcn_mfma_f32_16x16x32_bf16(af[kk], wf[(ISENC ? 0 : 16) + kk], acc, 0, 0, 0);
  if (sub < 2) {
#pragma unroll
    for (int r = 0; r < 4; ++r)
      lds_rz[sub][half][quad * 4 + r][l15] = acc[r] + bh + giv[r];
    __syncthreads();
  } else {
    __syncthreads();
    const int pn = p ^ 1;
#pragma unroll
    for (int r = 0; r < 4; ++r) {
      const int b = quad * 4 + r;
      const float rp = lds_rz[0][half][b][l15];
      const float zp = lds_rz[1][half][b][l15];
      const float rr = 1.f / (1.f + __expf(-rp));
      const float zz = 1.f / (1.f + __expf(-zp));
      const float nn = tanhf(giv[r] + rr * (acc[r] + bh));   // n = tanh(gi_n + r*(gh_n + bhh_n))
      const float hv = (1.f - zz) * nn + zz * hreg[r];
      hreg[r] = hv;
      const u16 h16 = f2b(hv);
      a.ha[pn * 8192 + b * 512 + jc] = h16;
      if (ISENC) a.eo[((size_t)(b * 64 + step)) * 512 + jc] = h16;
      else       a.hcat[((size_t)(step * 16 + b)) * 1024 + jc] = h16;
    }
  }
}

__global__ void __launch_bounds__(384) rec_kernel(RecArgs a) {
  __shared__ float lds_rz[2][2][16][16];
  const int tid = threadIdx.x;
  const int wave = tid >> 6, lane = tid & 63;
  const int l15 = lane & 15, quad = lane >> 4;
  const int J = blockIdx.x * 32;
  const int sub = wave % 3, half = wave / 3;

  // ---- one-time: stage W_hh gate fragments into registers (bf16) ----
  short8 wf[32];
  const int row = sub * 512 + J + half * 16 + l15;   // gate row of W_hh
  const float* pe = a.Whe + (size_t)row * 512 + quad * 8;
  const float* pd = a.Whd + (size_t)row * 512 + quad * 8;
#pragma unroll
  for (int kk = 0; kk < 16; ++kk) {
    wf[kk]      = pack8(*(const float4*)(pe + kk * 32), *(const float4*)(pe + kk * 32 + 4));
    wf[16 + kk] = pack8(*(const float4*)(pd + kk * 32), *(const float4*)(pd + kk * 32 + 4));
  }
  const int jc = J + half * 16 + l15;
  const float bhe = a.bhe[sub * 512 + jc];
  const float bhd = a.bhd[sub * 512 + jc];

  float hreg[4] = {0.f, 0.f, 0.f, 0.f};
  // zero-init h buffer 0 (own columns; the 16 blocks cover all 512)
  if (sub == 2) {
#pragma unroll
    for (int r = 0; r < 4; ++r)
      a.ha[(quad * 4 + r) * 512 + jc] = 0;
  }
  int gen = 0;
  gridbar(a.bar, ++gen);

  // ---- encoder: 1 barrier / step ----
  for (int s = 0; s < S_; ++s) {
    gate_phase<1>(a, wave, l15, quad, J, s, s & 1, wf, bhe, hreg, lds_rz);
    gridbar(a.bar, ++gen);
  }

  // ---- decoder: 1 barrier / step, none after the last ----
  for (int t = 0; t < TD; ++t) {
    gate_phase<0>(a, wave, l15, quad, J, t, t & 1, wf, bhd, hreg, lds_rz);
    if (t < TD - 1) gridbar(a.bar, ++gen);
  }
}

// ---------------- attention, hoisted out of the loop ----------------
// 1008 independent blocks: m = t*16+b. Reads h_t (hcat[:,0:512]) and enc_out,
// writes attn into hcat[:,512:1024].
__global__ void __launch_bounds__(512) attn_kernel(
    const u16* __restrict__ eo16, u16* __restrict__ hcat)
{
  __shared__ float sc[64][9];
  __shared__ float wts[64];
  const int m = blockIdx.x, t = m >> 4, b = m & 15;
  (void)t;
  const int tid = threadIdx.x;
  const u16* eo = eo16 + (size_t)b * 64 * 512;
  const u16* h = hcat + (size_t)m * 1024;
  {
    const int s = tid >> 3, q = tid & 7;
    const u16* ep = eo + s * 512 + q * 64;
    const u16* hp = h + q * 64;
    float acc = 0.f;
#pragma unroll
    for (int u = 0; u < 8; ++u) {
      short8 e8 = *(const short8*)(ep + u * 8);
      short8 h8 = *(const short8*)(hp + u * 8);
#pragma unroll
      for (int i = 0; i < 8; ++i) acc += b2f((u16)e8[i]) * b2f((u16)h8[i]);
    }
    sc[s][q] = acc;
  }
  __syncthreads();
  if (tid < 64) {
    float v = 0.f;
#pragma unroll
    for (int u = 0; u < 8; ++u) v += sc[tid][u];
    float mx = v;
#pragma unroll
    for (int d = 1; d < 64; d <<= 1) mx = fmaxf(mx, __shfl_xor(mx, d));
    float e = __expf(v - mx);
    float sum = e;
#pragma unroll
    for (int d = 1; d < 64; d <<= 1) sum += __shfl_xor(sum, d);
    wts[tid] = e / sum;
  }
  __syncthreads();
  {
    const int j = tid;
    float acc = 0.f;
#pragma unroll 8
    for (int s2 = 0; s2 < 64; ++s2) acc += wts[s2] * b2f(eo[s2 * 512 + j]);
    hcat[(size_t)m * 1024 + 512 + j] = f2b(acc);
  }
}

// ---------------- loss (f32 logits) ----------------
__global__ void __launch_bounds__(256) loss_rows_kernel(
    const float* __restrict__ logits, const int* __restrict__ y, float* __restrict__ nll)
{
  __shared__ float wred[4];
  const int m = blockIdx.x;               // m = t*16+b
  const int t = m >> 4, b = m & 15;
  const float* row = logits + ((size_t)b * TD + t) * V_;
  const int tid = threadIdx.x;
  const int lane = tid & 63, wave = tid >> 6;

  float mx = -1e30f;
  for (int c = tid; c < 8000; c += 256) {
    float4 v = ((const float4*)row)[c];
    mx = fmaxf(mx, fmaxf(fmaxf(v.x, v.y), fmaxf(v.z, v.w)));
  }
#pragma unroll
  for (int d = 1; d < 64; d <<= 1) mx = fmaxf(mx, __shfl_xor(mx, d));
  if (lane == 0) wred[wave] = mx;
  __syncthreads();
  mx = fmaxf(fmaxf(wred[0], wred[1]), fmaxf(wred[2], wred[3]));
  __syncthreads();

  float sum = 0.f;
  for (int c = tid; c < 8000; c += 256) {
    float4 v = ((const float4*)row)[c];
    sum += __expf(v.x - mx) + __expf(v.y - mx) + __expf(v.z - mx) + __expf(v.w - mx);
  }
#pragma unroll
  for (int d = 1; d < 64; d <<= 1) sum += __shfl_xor(sum, d);
  if (lane == 0) wred[wave] = sum;
  __syncthreads();
  if (tid == 0) {
    float stot = wred[0] + wred[1] + wred[2] + wred[3];
    int tok = y[b * 64 + t + 1];
    nll[m] = mx + logf(stot) - row[tok];
  }
}

__global__ void __launch_bounds__(256) loss_final_kernel(const float* __restrict__ nll, float* __restrict__ out) {
  __shared__ float wred[4];
  const int tid = threadIdx.x;
  float s = 0.f;
  for (int i = tid; i < MROWS; i += 256) s += nll[i];
#pragma unroll
  for (int d = 1; d < 64; d <<= 1) s += __shfl_xor(s, d);
  if ((tid & 63) == 0) wred[tid >> 6] = s;
  __syncthreads();
  if (tid == 0) out[0] = (wred[0] + wred[1] + wred[2] + wred[3]) / 1008.f;
}

// ---------------- launch ----------------
extern "C" void kernel_launch(void* const* d_in, const int* in_sizes, int n_in,
                              void* d_out, int out_size, void* d_ws, size_t ws_size,
                              hipStream_t stream)
{
  const int*   x       = (const int*)d_in[0];
  const int*   y       = (const int*)d_in[1];
  const float* emb_enc = (const float*)d_in[2];
  const float* W_ih_e  = (const float*)d_in[3];
  const float* W_hh_e  = (const float*)d_in[4];
  const float* b_ih_e  = (const float*)d_in[5];
  const float* b_hh_e  = (const float*)d_in[6];
  const float* emb_dec = (const float*)d_in[7];
  const float* W_ih_d  = (const float*)d_in[8];
  const float* W_hh_d  = (const float*)d_in[9];
  const float* b_ih_d  = (const float*)d_in[10];
  const float* b_hh_d  = (const float*)d_in[11];
  const float* W_c     = (const float*)d_in[12];
  const float* b_c     = (const float*)d_in[13];
  const float* W_out   = (const float*)d_in[14];
  const float* b_out   = (const float*)d_in[15];

  // ws layout (16,684,992 B total — within the proven 16.7 MB footprint)
  char* ws = (char*)d_ws;
  float* gi_enc = (float*)(ws + 0);           //  6,291,456
  float* gi_dec = (float*)(ws + 6291456);     //  6,193,152  -> 12,484,608
  u16* embx     = (u16*)(ws + 12484608);      //  1,048,576  -> 13,533,184 (dead after gi GEMMs)
  u16* emby     = (u16*)(ws + 13533184);      //  1,032,192  -> 14,565,376 (dead after gi GEMMs)
  u16* hcat     = (u16*)(ws + 12484608);      //  2,064,384  -> 14,548,992 (reuses embx/emby region)
  u16* Dm       = (u16*)(ws + 14565376);      //  1,032,192  -> 15,597,568
  u16* eo16     = (u16*)(ws + 15597568);      //  1,048,576  -> 16,646,144
  u16* ha16     = (u16*)(ws + 16646144);      //     32,768  -> 16,678,912
  float* nll    = (float*)(ws + 16678912);    //      4,032  -> 16,682,944
  int* bar      = (int*)(ws + 16682944);      //      2,048  -> 16,684,992

  hipMemsetAsync(bar, 0, 2048, stream);       // barrier generation slots (graph-capture safe)

  gather_kernel<<<dim3(B_ * S_ + MROWS), dim3(256), 0, stream>>>(x, y, emb_enc, emb_dec, embx, emby);

  gemm_bt<0><<<dim3(12, 16), dim3(256), 0, stream>>>(embx, W_ih_e, b_ih_e, (void*)gi_enc, 1024, G3, 512);
  gemm_bt<0><<<dim3(12, 16), dim3(256), 0, stream>>>(emby, W_ih_d, b_ih_d, (void*)gi_dec, MROWS, G3, 512);

  RecArgs ra{gi_enc, gi_dec, W_hh_e, W_hh_d, b_hh_e, b_hh_d, eo16, ha16, hcat, bar};
  rec_kernel<<<dim3(NBLK), dim3(384), 0, stream>>>(ra);

  attn_kernel<<<dim3(MROWS), dim3(512), 0, stream>>>(eo16, hcat);

  // Dm = tanh([h;attn] @ W_c^T + b_c)  (bf16 out)
  gemm_bt<2><<<dim3(4, 16), dim3(256), 0, stream>>>(hcat, W_c, b_c, (void*)Dm, MROWS, 512, 1024);

  gemm_bt<1><<<dim3(250, 16), dim3(256), 0, stream>>>(Dm, W_out, b_out, d_out, MROWS, V_, 512);
  loss_rows_kernel<<<dim3(MROWS), dim3(256), 0, stream>>>((const float*)d_out, y, nll);
  loss_final_kernel<<<dim3(1), dim3(256), 0, stream>>>(nll, ((float*)d_out) + (size_t)MROWS * V_);
}

// Round 5
// 1187.747 us; speedup vs baseline: 4.5308x; 1.0364x over previous
//
#include <hip/hip_runtime.h>

typedef unsigned short u16;
typedef unsigned int u32;
typedef __attribute__((ext_vector_type(8))) short short8;
typedef __attribute__((ext_vector_type(4))) float floatx4;

#define B_ 16
#define S_ 64
#define H_ 512
#define V_ 32000
#define G3 1536   // 3*H
#define TD 63     // T-1
#define MROWS 1008
#define NBLK 16   // rec_kernel blocks (one per 32-col slice of h)

__device__ __forceinline__ float b2f(u16 u) {
  union { u32 i; float f; } c; c.i = ((u32)u) << 16; return c.f;
}
__device__ __forceinline__ u16 f2b(float f) {
  union { float f; u32 i; } c; c.f = f;
  u32 u = c.i;
  return (u16)((u + 0x7FFFu + ((u >> 16) & 1u)) >> 16);  // RNE
}
__device__ __forceinline__ short8 pack8(float4 a, float4 b) {
  short8 r;
  r[0] = (short)f2b(a.x); r[1] = (short)f2b(a.y); r[2] = (short)f2b(a.z); r[3] = (short)f2b(a.w);
  r[4] = (short)f2b(b.x); r[5] = (short)f2b(b.y); r[6] = (short)f2b(b.z); r[7] = (short)f2b(b.w);
  return r;
}

// ---------------- embedding gather (f32 -> bf16) ----------------
__global__ void __launch_bounds__(256) gather_kernel(
    const int* __restrict__ x, const int* __restrict__ y,
    const float* __restrict__ emb_enc, const float* __restrict__ emb_dec,
    u16* __restrict__ ex, u16* __restrict__ ey)
{
  const int r = blockIdx.x, tid = threadIdx.x;
  if (r < B_ * S_) {                       // encoder row m = b*64+s
    int tok = x[r];
    float2 v = ((const float2*)(emb_enc + (size_t)tok * H_))[tid];
    ((u32*)(ex + (size_t)r * H_))[tid] = (u32)f2b(v.x) | ((u32)f2b(v.y) << 16);
  } else {                                 // decoder row m = t*16+b
    int m = r - B_ * S_;
    int t = m >> 4, b = m & 15;
    int tok = y[b * 64 + t];
    float2 v = ((const float2*)(emb_dec + (size_t)tok * H_))[tid];
    ((u32*)(ey + (size_t)m * H_))[tid] = (u32)f2b(v.x) | ((u32)f2b(v.y) << 16);
  }
}

// ---------------- bf16-MFMA GEMM: C = A @ B^T + bias ----------------
// A:[M,K] bf16, B:[N,K] f32 (converted to bf16 while staging), bias f32[N]
// MODE 0: C fp32 [M,N].
// MODE 1: C fp32 into d_out, row remap m=t*16+b -> (b*63+t)
// MODE 2: C = tanh(.) -> bf16 [M,N]
// SWAP 1: blockIdx.x indexes M-tiles, blockIdx.y indexes N-tiles (L2 locality:
//         dispatch-adjacent blocks share one B panel).
template <int MODE, int SWAP = 0>
__global__ void __launch_bounds__(256) gemm_bt(
    const u16* __restrict__ A, const float* __restrict__ Bm,
    const float* __restrict__ bias, void* __restrict__ Cout, int M, int N, int K)
{
  __shared__ u16 As[64 * 40];
  __shared__ u16 Bs[128 * 40];
  const int tid = threadIdx.x;
  const int wave = tid >> 6, lane = tid & 63;
  const int l15 = lane & 15, quad = lane >> 4;
  const int m0 = (SWAP ? blockIdx.x : blockIdx.y) * 64;
  const int n0 = (SWAP ? blockIdx.y : blockIdx.x) * 128;
  floatx4 acc[4][2] = {};

  for (int kk = 0; kk < K; kk += 32) {
    {
      int row = tid >> 2, ch = tid & 3;
      short8 v = {};
      int gm = m0 + row;
      if (gm < M) v = *(const short8*)(A + (size_t)gm * K + kk + ch * 8);
      *(short8*)(As + row * 40 + ch * 8) = v;
    }
#pragma unroll
    for (int i = 0; i < 4; ++i) {
      int idx = tid + i * 256;
      int row = idx >> 3, c4 = idx & 7;
      int gn = n0 + row;
      float4 w = *(const float4*)(Bm + (size_t)gn * K + kk + c4 * 4);
      uint2 p;
      p.x = (u32)f2b(w.x) | ((u32)f2b(w.y) << 16);
      p.y = (u32)f2b(w.z) | ((u32)f2b(w.w) << 16);
      *(uint2*)(Bs + row * 40 + c4 * 4) = p;
    }
    __syncthreads();
    short8 af[4], bfr[2];
#pragma unroll
    for (int mt = 0; mt < 4; ++mt)
      af[mt] = *(const short8*)(As + (mt * 16 + l15) * 40 + quad * 8);
#pragma unroll
    for (int nt = 0; nt < 2; ++nt)
      bfr[nt] = *(const short8*)(Bs + (wave * 32 + nt * 16 + l15) * 40 + quad * 8);
#pragma unroll
    for (int mt = 0; mt < 4; ++mt)
#pragma unroll
      for (int nt = 0; nt < 2; ++nt)
        acc[mt][nt] = __builtin_amdgcn_mfma_f32_16x16x32_bf16(af[mt], bfr[nt], acc[mt][nt], 0, 0, 0);
    __syncthreads();
  }
#pragma unroll
  for (int mt = 0; mt < 4; ++mt) {
#pragma unroll
    for (int nt = 0; nt < 2; ++nt) {
      int gn = n0 + wave * 32 + nt * 16 + l15;
      float bv = bias[gn];
#pragma unroll
      for (int r = 0; r < 4; ++r) {
        int gm = m0 + mt * 16 + quad * 4 + r;  // C/D: col=lane&15, row=quad*4+reg
        if (gm < M) {
          float v = acc[mt][nt][r] + bv;
          if (MODE == 0) {
            ((float*)Cout)[(size_t)gm * N + gn] = v;
          } else if (MODE == 1) {
            int tt = gm >> 4, bb = gm & 15;
            ((float*)Cout)[((size_t)bb * TD + tt) * V_ + gn] = v;
          } else {
            ((u16*)Cout)[(size_t)gm * N + gn] = f2b(tanhf(v));
          }
        }
      }
    }
  }
}

// ---------------- cooperative recurrence (GRU chain ONLY) ----------------
// BYTE-IDENTICAL to the round-2 version measured at 700 us (bisection: the
// rounds-3/4 restructures are reverted wholesale).
struct RecArgs {
  const float* gi_enc;   // [1024][1536]  row = b*64+s
  const float* gi_dec;   // [1008][1536]  row = t*16+b
  const float* Whe;      // [1536][512] raw W_hh_e
  const float* Whd;      // [1536][512] raw W_hh_d
  const float* bhe;      // [1536]
  const float* bhd;      // [1536]
  u16* eo;               // enc_out bf16 [16][64][512]
  u16* ha;               // [2][16][512] bf16 h exchange
  u16* hcat;             // [1008][1024] bf16: cols 0..511 = h_t, 512..1023 = attn (later)
  int* bar;              // 16 arrival slots, 128B apart, generation-tagged
};

// Symmetric generation barrier: no RMW contention, no reset round.
__device__ __forceinline__ void gridbar(int* slots, int gen) {
  __syncthreads();
  if (threadIdx.x < 16) {
    if (threadIdx.x == 0) {
      __builtin_amdgcn_fence(__ATOMIC_RELEASE, "agent");
      __hip_atomic_store(slots + (int)blockIdx.x * 32, gen, __ATOMIC_RELAXED, __HIP_MEMORY_SCOPE_AGENT);
    }
    while (__hip_atomic_load(slots + (int)threadIdx.x * 32, __ATOMIC_RELAXED, __HIP_MEMORY_SCOPE_AGENT) < gen) {}
    __builtin_amdgcn_fence(__ATOMIC_ACQUIRE, "agent");
  }
  __syncthreads();
}

// One GRU gate+update phase. p = read parity (reads ha[p], writes ha[p^1]).
template <int ISENC>
__device__ __forceinline__ void gate_phase(const RecArgs& a, int wave, int l15, int quad,
    int J, int step, int p, const short8* wf, float bh, float* hreg,
    float (&lds_rz)[2][2][16][16])
{
  const int sub = wave % 3, half = wave / 3;
  const int jc = J + half * 16 + l15;
  const float* gi = ISENC ? a.gi_enc : a.gi_dec;
  float giv[4];
#pragma unroll
  for (int r = 0; r < 4; ++r) {
    const int b = quad * 4 + r;
    const int row = ISENC ? (b * 64 + step) : (step * 16 + b);
    giv[r] = gi[(size_t)row * G3 + sub * 512 + jc];
  }
  const u16* hb = a.ha + p * 8192 + l15 * 512 + quad * 8;
  short8 af[16];
#pragma unroll
  for (int kk = 0; kk < 16; ++kk) af[kk] = *(const short8*)(hb + kk * 32);
  floatx4 acc = {0.f, 0.f, 0.f, 0.f};
#pragma unroll
  for (int kk = 0; kk < 16; ++kk)
    acc = __builtin_amdgcn_mfma_f32_16x16x32_bf16(af[kk], wf[(ISENC ? 0 : 16) + kk], acc, 0, 0, 0);
  if (sub < 2) {
#pragma unroll
    for (int r = 0; r < 4; ++r)
      lds_rz[sub][half][quad * 4 + r][l15] = acc[r] + bh + giv[r];
    __syncthreads();
  } else {
    __syncthreads();
    const int pn = p ^ 1;
#pragma unroll
    for (int r = 0; r < 4; ++r) {
      const int b = quad * 4 + r;
      const float rp = lds_rz[0][half][b][l15];
      const float zp = lds_rz[1][half][b][l15];
      const float rr = 1.f / (1.f + __expf(-rp));
      const float zz = 1.f / (1.f + __expf(-zp));
      const float nn = tanhf(giv[r] + rr * (acc[r] + bh));   // n = tanh(gi_n + r*(gh_n + bhh_n))
      const float hv = (1.f - zz) * nn + zz * hreg[r];
      hreg[r] = hv;
      const u16 h16 = f2b(hv);
      a.ha[pn * 8192 + b * 512 + jc] = h16;
      if (ISENC) a.eo[((size_t)(b * 64 + step)) * 512 + jc] = h16;
      else       a.hcat[((size_t)(step * 16 + b)) * 1024 + jc] = h16;
    }
  }
}

__global__ void __launch_bounds__(384) rec_kernel(RecArgs a) {
  __shared__ float lds_rz[2][2][16][16];
  const int tid = threadIdx.x;
  const int wave = tid >> 6, lane = tid & 63;
  const int l15 = lane & 15, quad = lane >> 4;
  const int J = blockIdx.x * 32;
  const int sub = wave % 3, half = wave / 3;

  // ---- one-time: stage W_hh gate fragments into registers (bf16) ----
  short8 wf[32];
  const int row = sub * 512 + J + half * 16 + l15;   // gate row of W_hh
  const float* pe = a.Whe + (size_t)row * 512 + quad * 8;
  const float* pd = a.Whd + (size_t)row * 512 + quad * 8;
#pragma unroll
  for (int kk = 0; kk < 16; ++kk) {
    wf[kk]      = pack8(*(const float4*)(pe + kk * 32), *(const float4*)(pe + kk * 32 + 4));
    wf[16 + kk] = pack8(*(const float4*)(pd + kk * 32), *(const float4*)(pd + kk * 32 + 4));
  }
  const int jc = J + half * 16 + l15;
  const float bhe = a.bhe[sub * 512 + jc];
  const float bhd = a.bhd[sub * 512 + jc];

  float hreg[4] = {0.f, 0.f, 0.f, 0.f};
  // zero-init h buffer 0 (own columns; the 16 blocks cover all 512)
  if (sub == 2) {
#pragma unroll
    for (int r = 0; r < 4; ++r)
      a.ha[(quad * 4 + r) * 512 + jc] = 0;
  }
  int gen = 0;
  gridbar(a.bar, ++gen);

  // ---- encoder: 1 barrier / step ----
  for (int s = 0; s < S_; ++s) {
    gate_phase<1>(a, wave, l15, quad, J, s, s & 1, wf, bhe, hreg, lds_rz);
    gridbar(a.bar, ++gen);
  }

  // ---- decoder: 1 barrier / step, none after the last ----
  for (int t = 0; t < TD; ++t) {
    gate_phase<0>(a, wave, l15, quad, J, t, t & 1, wf, bhd, hreg, lds_rz);
    if (t < TD - 1) gridbar(a.bar, ++gen);
  }
}

// ---------------- attention, hoisted out of the loop ----------------
// 1008 independent blocks: m = t*16+b. Reads h_t (hcat[:,0:512]) and enc_out,
// writes attn into hcat[:,512:1024].
__global__ void __launch_bounds__(512) attn_kernel(
    const u16* __restrict__ eo16, u16* __restrict__ hcat)
{
  __shared__ float sc[64][9];
  __shared__ float wts[64];
  const int m = blockIdx.x, b = m & 15;
  const int tid = threadIdx.x;
  const u16* eo = eo16 + (size_t)b * 64 * 512;
  const u16* h = hcat + (size_t)m * 1024;
  {
    const int s = tid >> 3, q = tid & 7;
    const u16* ep = eo + s * 512 + q * 64;
    const u16* hp = h + q * 64;
    float acc = 0.f;
#pragma unroll
    for (int u = 0; u < 8; ++u) {
      short8 e8 = *(const short8*)(ep + u * 8);
      short8 h8 = *(const short8*)(hp + u * 8);
#pragma unroll
      for (int i = 0; i < 8; ++i) acc += b2f((u16)e8[i]) * b2f((u16)h8[i]);
    }
    sc[s][q] = acc;
  }
  __syncthreads();
  if (tid < 64) {
    float v = 0.f;
#pragma unroll
    for (int u = 0; u < 8; ++u) v += sc[tid][u];
    float mx = v;
#pragma unroll
    for (int d = 1; d < 64; d <<= 1) mx = fmaxf(mx, __shfl_xor(mx, d));
    float e = __expf(v - mx);
    float sum = e;
#pragma unroll
    for (int d = 1; d < 64; d <<= 1) sum += __shfl_xor(sum, d);
    wts[tid] = e / sum;
  }
  __syncthreads();
  {
    const int j = tid;
    float acc = 0.f;
#pragma unroll 8
    for (int s2 = 0; s2 < 64; ++s2) acc += wts[s2] * b2f(eo[s2 * 512 + j]);
    hcat[(size_t)m * 1024 + 512 + j] = f2b(acc);
  }
}

// ---------------- loss: single-pass online softmax over f32 logits ----------------
__global__ void __launch_bounds__(256) loss_rows_kernel(
    const float* __restrict__ logits, const int* __restrict__ y, float* __restrict__ nll)
{
  __shared__ float wm[4], ws_[4];
  const int m = blockIdx.x;               // m = t*16+b
  const int t = m >> 4, b = m & 15;
  const float* row = logits + ((size_t)b * TD + t) * V_;
  const int tid = threadIdx.x;
  const int lane = tid & 63, wave = tid >> 6;

  float mx = -1e30f, sum = 0.f;
  for (int c = tid; c < 8000; c += 256) {
    float4 v = ((const float4*)row)[c];
    float m4 = fmaxf(fmaxf(v.x, v.y), fmaxf(v.z, v.w));
    if (m4 > mx) { sum *= __expf(mx - m4); mx = m4; }
    sum += __expf(v.x - mx) + __expf(v.y - mx) + __expf(v.z - mx) + __expf(v.w - mx);
  }
#pragma unroll
  for (int d = 1; d < 64; d <<= 1) {
    float om = __shfl_xor(mx, d), os = __shfl_xor(sum, d);
    float nm = fmaxf(mx, om);
    sum = sum * __expf(mx - nm) + os * __expf(om - nm);
    mx = nm;
  }
  if (lane == 0) { wm[wave] = mx; ws_[wave] = sum; }
  __syncthreads();
  if (tid == 0) {
    float M = wm[0], S = ws_[0];
#pragma unroll
    for (int u = 1; u < 4; ++u) {
      float nm = fmaxf(M, wm[u]);
      S = S * __expf(M - nm) + ws_[u] * __expf(wm[u] - nm);
      M = nm;
    }
    int tok = y[b * 64 + t + 1];
    nll[m] = M + logf(S) - row[tok];
  }
}

__global__ void __launch_bounds__(256) loss_final_kernel(const float* __restrict__ nll, float* __restrict__ out) {
  __shared__ float wred[4];
  const int tid = threadIdx.x;
  float s = 0.f;
  for (int i = tid; i < MROWS; i += 256) s += nll[i];
#pragma unroll
  for (int d = 1; d < 64; d <<= 1) s += __shfl_xor(s, d);
  if ((tid & 63) == 0) wred[tid >> 6] = s;
  __syncthreads();
  if (tid == 0) out[0] = (wred[0] + wred[1] + wred[2] + wred[3]) / 1008.f;
}

// ---------------- launch ----------------
extern "C" void kernel_launch(void* const* d_in, const int* in_sizes, int n_in,
                              void* d_out, int out_size, void* d_ws, size_t ws_size,
                              hipStream_t stream)
{
  const int*   x       = (const int*)d_in[0];
  const int*   y       = (const int*)d_in[1];
  const float* emb_enc = (const float*)d_in[2];
  const float* W_ih_e  = (const float*)d_in[3];
  const float* W_hh_e  = (const float*)d_in[4];
  const float* b_ih_e  = (const float*)d_in[5];
  const float* b_hh_e  = (const float*)d_in[6];
  const float* emb_dec = (const float*)d_in[7];
  const float* W_ih_d  = (const float*)d_in[8];
  const float* W_hh_d  = (const float*)d_in[9];
  const float* b_ih_d  = (const float*)d_in[10];
  const float* b_hh_d  = (const float*)d_in[11];
  const float* W_c     = (const float*)d_in[12];
  const float* b_c     = (const float*)d_in[13];
  const float* W_out   = (const float*)d_in[14];
  const float* b_out   = (const float*)d_in[15];

  // ws layout (16,684,992 B total — within the proven footprint)
  char* ws = (char*)d_ws;
  float* gi_enc = (float*)(ws + 0);           //  6,291,456
  float* gi_dec = (float*)(ws + 6291456);     //  6,193,152  -> 12,484,608
  u16* embx     = (u16*)(ws + 12484608);      //  1,048,576  -> 13,533,184 (dead after gi GEMMs)
  u16* emby     = (u16*)(ws + 13533184);      //  1,032,192  -> 14,565,376 (dead after gi GEMMs)
  u16* hcat     = (u16*)(ws + 12484608);      //  2,064,384  -> 14,548,992 (reuses embx/emby region)
  u16* Dm       = (u16*)(ws + 14565376);      //  1,032,192  -> 15,597,568
  u16* eo16     = (u16*)(ws + 15597568);      //  1,048,576  -> 16,646,144
  u16* ha16     = (u16*)(ws + 16646144);      //     32,768  -> 16,678,912
  float* nll    = (float*)(ws + 16678912);    //      4,032  -> 16,682,944
  int* bar      = (int*)(ws + 16682944);      //      2,048  -> 16,684,992

  hipMemsetAsync(bar, 0, 2048, stream);       // barrier generation slots (graph-capture safe)

  gather_kernel<<<dim3(B_ * S_ + MROWS), dim3(256), 0, stream>>>(x, y, emb_enc, emb_dec, embx, emby);

  gemm_bt<0><<<dim3(12, 16), dim3(256), 0, stream>>>(embx, W_ih_e, b_ih_e, (void*)gi_enc, 1024, G3, 512);
  gemm_bt<0><<<dim3(12, 16), dim3(256), 0, stream>>>(emby, W_ih_d, b_ih_d, (void*)gi_dec, MROWS, G3, 512);

  RecArgs ra{gi_enc, gi_dec, W_hh_e, W_hh_d, b_hh_e, b_hh_d, eo16, ha16, hcat, bar};
  rec_kernel<<<dim3(NBLK), dim3(384), 0, stream>>>(ra);

  attn_kernel<<<dim3(MROWS), dim3(512), 0, stream>>>(eo16, hcat);

  // Dm = tanh([h;attn] @ W_c^T + b_c)  (bf16 out)
  gemm_bt<2><<<dim3(4, 16), dim3(256), 0, stream>>>(hcat, W_c, b_c, (void*)Dm, MROWS, 512, 1024);

  // logits: SWAP grid (M-tiles fast) so dispatch-adjacent blocks share a W_out panel
  gemm_bt<1, 1><<<dim3(16, 250), dim3(256), 0, stream>>>(Dm, W_out, b_out, d_out, MROWS, V_, 512);
  loss_rows_kernel<<<dim3(MROWS), dim3(256), 0, stream>>>((const float*)d_out, y, nll);
  loss_final_kernel<<<dim3(1), dim3(256), 0, stream>>>(nll, ((float*)d_out) + (size_t)MROWS * V_);
}